// Round 1
// baseline (776.943 us; speedup 1.0000x reference)
//
#include <hip/hip_runtime.h>

typedef _Float16 f16;
typedef __attribute__((ext_vector_type(8))) _Float16 f16x8;
typedef __attribute__((ext_vector_type(4))) float f32x4;

#define LDK 40   // LDS row stride (f16) for 32-wide K staging tiles (proj GEMMs)
#define SST 1032 // score LDS row stride in f16: 2064 B -> 4-bank row skew, 2-way max
#define BST 72   // 64x64 B-tile stride in f16: 144 B -> 4-bank row skew

// ---- staging helper: tile is 64 rows x 32 K-cols, 256 threads ----
__device__ __forceinline__ void stage_f16g(const f16* __restrict__ src, int ld, f16* dst) {
    int t = threadIdx.x;
    int row = t >> 2;
    int c0 = (t & 3) * 8;
    *(f16x8*)(dst + row * LDK + c0) = *(const f16x8*)(src + (size_t)row * ld + c0);
}

// ---- MFMA core: 4 waves, each computes 32x32 of a 64x64 C tile ----
// A-frag: A[m=lane&15][k=(lane>>4)*8 + j]; B-frag: B[n=lane&15][k=...]
// C/D:    D[m=(lane>>4)*4 + reg][n=lane&15]
__device__ __forceinline__ void mma_step(const f16* As, const f16* Bs, int m_off, int n_off,
                                         f32x4 acc[2][2]) {
    int lane = threadIdx.x & 63;
    int r = lane & 15;
    int kq = (lane >> 4) * 8;
    f16x8 a0 = *(const f16x8*)(As + (m_off + r) * LDK + kq);
    f16x8 a1 = *(const f16x8*)(As + (m_off + 16 + r) * LDK + kq);
    f16x8 b0 = *(const f16x8*)(Bs + (n_off + r) * LDK + kq);
    f16x8 b1 = *(const f16x8*)(Bs + (n_off + 16 + r) * LDK + kq);
    acc[0][0] = __builtin_amdgcn_mfma_f32_16x16x32_f16(a0, b0, acc[0][0], 0, 0, 0);
    acc[0][1] = __builtin_amdgcn_mfma_f32_16x16x32_f16(a0, b1, acc[0][1], 0, 0, 0);
    acc[1][0] = __builtin_amdgcn_mfma_f32_16x16x32_f16(a1, b0, acc[1][0], 0, 0, 0);
    acc[1][1] = __builtin_amdgcn_mfma_f32_16x16x32_f16(a1, b1, acc[1][1], 0, 0, 0);
}

#define GEMM_PROLOGUE()                                         \
    __shared__ __align__(16) f16 As[64 * LDK];                  \
    __shared__ __align__(16) f16 Bs[64 * LDK];                  \
    const int w = threadIdx.x >> 6;                             \
    const int m_off = (w & 1) * 32, n_off = (w >> 1) * 32;      \
    const int lane = threadIdx.x & 63;                          \
    f32x4 zero = {0.f, 0.f, 0.f, 0.f};                          \
    f32x4 acc[2][2] = {{zero, zero}, {zero, zero}};

// ---- convert all fp32 inputs/weights to f16 once ----
__global__ __launch_bounds__(256) void cvt_all(
    const float* __restrict__ q, const float* __restrict__ k, const float* __restrict__ v,
    const float* __restrict__ pe, const float* __restrict__ Wq, const float* __restrict__ Wk,
    const float* __restrict__ Wv, const float* __restrict__ Wp, const float* __restrict__ Wo,
    f16* __restrict__ dst) {
    const int seg = blockIdx.y;
    const float* srcs[9] = {q, k, v, pe, Wq, Wk, Wv, Wp, Wo};
    const int sz = (seg < 3) ? 4194304 : 1048576;
    const size_t off = (seg < 3) ? (size_t)seg * 4194304
                                 : (size_t)12582912 + (size_t)(seg - 3) * 1048576;
    const size_t i0 = ((size_t)blockIdx.x * 256 + threadIdx.x) * 16;
    if (i0 >= (size_t)sz) return;
    const float* s = srcs[seg] + i0;
    f16* d = dst + off + i0;
#pragma unroll
    for (int half = 0; half < 2; ++half) {
        float4 u = *(const float4*)(s + half * 8);
        float4 w = *(const float4*)(s + half * 8 + 4);
        f16x8 h;
        h[0] = (f16)u.x; h[1] = (f16)u.y; h[2] = (f16)u.z; h[3] = (f16)u.w;
        h[4] = (f16)w.x; h[5] = (f16)w.y; h[6] = (f16)w.z; h[7] = (f16)w.w;
        *(f16x8*)(d + half * 8) = h;
    }
}

// ---- batched Q/K/V projection: grid.z selects which ----
__global__ __launch_bounds__(256) void proj_qkv(
    const f16* __restrict__ qf, const f16* __restrict__ kf, const f16* __restrict__ vf,
    const f16* __restrict__ Wqf, const f16* __restrict__ Wkf, const f16* __restrict__ Wvf,
    const float* __restrict__ bq, const float* __restrict__ bk, const float* __restrict__ bv,
    const float* __restrict__ pbu, const float* __restrict__ pbv,
    f16* __restrict__ q_u, f16* __restrict__ q_v, f16* __restrict__ kh,
    f16* __restrict__ vh) {
    GEMM_PROLOGUE();
    const int z = blockIdx.z;
    const f16* A = (z == 0) ? qf : (z == 1) ? kf : vf;
    const f16* W = (z == 0) ? Wqf : (z == 1) ? Wkf : Wvf;
    const float* bias = (z == 0) ? bq : (z == 1) ? bk : bv;
    const int m0 = blockIdx.y * 64, n0 = blockIdx.x * 64;
    for (int k0 = 0; k0 < 1024; k0 += 32) {
        stage_f16g(A + (size_t)m0 * 1024 + k0, 1024, As);
        stage_f16g(W + (size_t)n0 * 1024 + k0, 1024, Bs);
        __syncthreads();
        mma_step(As, Bs, m_off, n_off, acc);
        __syncthreads();
    }
#pragma unroll
    for (int mt = 0; mt < 2; ++mt)
#pragma unroll
        for (int nt = 0; nt < 2; ++nt)
#pragma unroll
            for (int rr = 0; rr < 4; ++rr) {
                int m = m0 + m_off + mt * 16 + (lane >> 4) * 4 + rr;
                int n = n0 + n_off + nt * 16 + (lane & 15);
                float base = acc[mt][nt][rr] + bias[n];
                int b = m >> 10, t = m & 1023, h = n >> 6, d = n & 63;
                size_t idx = ((size_t)((b * 16 + h) * 1024 + t)) * 64 + d;
                if (z == 0) {
                    q_u[idx] = (f16)(base + pbu[n]);
                    q_v[idx] = (f16)(base + pbv[n]);
                } else if (z == 1) {
                    kh[idx] = (f16)base;
                } else {
                    vh[idx] = (f16)base;
                }
            }
}

// ---- P projection (no bias): pp[h][pos][64] ----
__global__ __launch_bounds__(256) void proj_p(const f16* __restrict__ A,
                                              const f16* __restrict__ W,
                                              f16* __restrict__ o1) {
    GEMM_PROLOGUE();
    const int m0 = blockIdx.y * 64;
    const int n0 = blockIdx.x * 64;
    for (int k0 = 0; k0 < 1024; k0 += 32) {
        stage_f16g(A + (size_t)m0 * 1024 + k0, 1024, As);
        stage_f16g(W + (size_t)n0 * 1024 + k0, 1024, Bs);
        __syncthreads();
        mma_step(As, Bs, m_off, n_off, acc);
        __syncthreads();
    }
#pragma unroll
    for (int mt = 0; mt < 2; ++mt)
#pragma unroll
        for (int nt = 0; nt < 2; ++nt)
#pragma unroll
            for (int rr = 0; rr < 4; ++rr) {
                int m = m0 + m_off + mt * 16 + (lane >> 4) * 4 + rr;
                int n = n0 + n_off + nt * 16 + (lane & 15);
                int h = n >> 6, d = n & 63;
                o1[((size_t)h * 1024 + m) * 64 + d] = (f16)acc[mt][nt][rr];
            }
}

// ---- fully fused attention: BD -> rel_shift -> +AC,scale -> softmax -> attn + PV ----
// grid (16 row-tiles, 64 bh), 256 threads. Scores for 64 rows x 1024 cols live in LDS.
__global__ __launch_bounds__(256) void fused_attn(
    const f16* __restrict__ q_u, const f16* __restrict__ q_v,
    const f16* __restrict__ kh, const f16* __restrict__ pp,
    const f16* __restrict__ vh, const int* __restrict__ mask,
    float* __restrict__ attn, f16* __restrict__ oh) {
    __shared__ __align__(16) f16 Ssc[64 * SST];   // 129 KB score tile
    __shared__ __align__(16) f16 Bt[64 * BST];    // 9 KB B staging (pp / kh / V^T)
    __shared__ __align__(16) f16 rawX[1024];      // raw BD row i0+64 (rel_shift wrap)
    __shared__ __align__(16) f16 qxrow[64];       // q_v row i0+64

    const int bh = blockIdx.y;
    const int b = bh >> 4, h = bh & 15;
    const int i0 = blockIdx.x * 64;
    const int tid = threadIdx.x;
    const int w = tid >> 6;
    const int lane = tid & 63;
    const int m_off = (w & 1) * 32, n_off = (w >> 1) * 32;
    const int fr = lane & 15;          // fragment row index (m or n)
    const int kq = (lane >> 4) * 8;    // fragment k offset
    const f32x4 zero = {0.f, 0.f, 0.f, 0.f};

    const f16* Qu = q_u + (size_t)bh * 65536;
    const f16* Qv = q_v + (size_t)bh * 65536;
    const f16* Kh = kh + (size_t)bh * 65536;
    const f16* Pp = pp + (size_t)h * 65536;
    const f16* Vh = vh + (size_t)bh * 65536;

    // A-fragments (q_u, q_v) in registers for all 16 col-tiles: [mt][ks]
    f16x8 qu_f[2][2], qv_f[2][2];
#pragma unroll
    for (int mt = 0; mt < 2; ++mt)
#pragma unroll
        for (int ks = 0; ks < 2; ++ks) {
            size_t off = (size_t)(i0 + m_off + mt * 16 + fr) * 64 + ks * 32 + kq;
            qu_f[mt][ks] = *(const f16x8*)(Qu + off);
            qv_f[mt][ks] = *(const f16x8*)(Qv + off);
        }

    if (i0 + 64 < 1024 && tid < 8)
        *(f16x8*)(qxrow + tid * 8) = *(const f16x8*)(Qv + (size_t)(i0 + 64) * 64 + tid * 8);

    // ---- phase 1: raw BD = q_v @ pp^T -> Ssc (f16) ----
    for (int j0 = 0; j0 < 1024; j0 += 64) {
        {
            int rrow = tid >> 2, c0 = (tid & 3) * 16;
            const f16* s = Pp + (size_t)(j0 + rrow) * 64 + c0;
            *(f16x8*)(Bt + rrow * BST + c0) = *(const f16x8*)(s);
            *(f16x8*)(Bt + rrow * BST + c0 + 8) = *(const f16x8*)(s + 8);
        }
        __syncthreads();
        f32x4 acc[2][2] = {{zero, zero}, {zero, zero}};
#pragma unroll
        for (int ks = 0; ks < 2; ++ks) {
            f16x8 b0 = *(const f16x8*)(Bt + (n_off + fr) * BST + ks * 32 + kq);
            f16x8 b1 = *(const f16x8*)(Bt + (n_off + 16 + fr) * BST + ks * 32 + kq);
            acc[0][0] = __builtin_amdgcn_mfma_f32_16x16x32_f16(qv_f[0][ks], b0, acc[0][0], 0, 0, 0);
            acc[0][1] = __builtin_amdgcn_mfma_f32_16x16x32_f16(qv_f[0][ks], b1, acc[0][1], 0, 0, 0);
            acc[1][0] = __builtin_amdgcn_mfma_f32_16x16x32_f16(qv_f[1][ks], b0, acc[1][0], 0, 0, 0);
            acc[1][1] = __builtin_amdgcn_mfma_f32_16x16x32_f16(qv_f[1][ks], b1, acc[1][1], 0, 0, 0);
        }
#pragma unroll
        for (int mt = 0; mt < 2; ++mt)
#pragma unroll
            for (int nt = 0; nt < 2; ++nt)
#pragma unroll
                for (int rr = 0; rr < 4; ++rr) {
                    int m = m_off + mt * 16 + (lane >> 4) * 4 + rr;
                    int c = j0 + n_off + nt * 16 + fr;
                    Ssc[m * SST + c] = (f16)acc[mt][nt][rr];
                }
        __syncthreads();
    }

    // ---- phase 1b: rawX[p] = q_v[i0+64] . pp[p] (VALU; tiny) ----
    if (i0 + 64 < 1024) {
        int p = tid * 4;
#pragma unroll
        for (int pi = 0; pi < 4; ++pi) {
            const f16* pr = Pp + (size_t)(p + pi) * 64;
            float sacc = 0.f;
#pragma unroll
            for (int c = 0; c < 64; c += 8) {
                f16x8 pv = *(const f16x8*)(pr + c);
                f16x8 qv8 = *(const f16x8*)(qxrow + c);
#pragma unroll
                for (int j = 0; j < 8; ++j) sacc += (float)pv[j] * (float)qv8[j];
            }
            rawX[p + pi] = (f16)sacc;
        }
    }

    // ---- phase 2: rel_shift, in place, ordered 4-row chunks ----
    // shifted[r][s] = raw[r][s+1023-r] (s<=r) | 0 (s==r+1) | raw[r+1][s-r-2] (s>=r+2)
    for (int cc = 0; cc < 16; ++cc) {
        int lr = cc * 4 + w;       // wave w owns row lr of this chunk
        int r = i0 + lr;
        int s0 = lane * 16;
        f16 tmp[16];
#pragma unroll
        for (int j = 0; j < 16; ++j) {
            int s = s0 + j;
            f16 val;
            if (s <= r) val = Ssc[lr * SST + (s + 1023 - r)];
            else if (s == r + 1) val = (f16)0.f;
            else val = (lr == 63) ? rawX[s - r - 2] : Ssc[(lr + 1) * SST + (s - r - 2)];
            tmp[j] = val;
        }
        __syncthreads();
        f16x8 o0, o1;
#pragma unroll
        for (int j = 0; j < 8; ++j) { o0[j] = tmp[j]; o1[j] = tmp[8 + j]; }
        *(f16x8*)(Ssc + lr * SST + s0) = o0;
        *(f16x8*)(Ssc + lr * SST + s0 + 8) = o1;
        __syncthreads();
    }

    // ---- phase 3: scores = (shiftedBD + q_u @ kh^T) * 0.125, in place ----
    for (int j0 = 0; j0 < 1024; j0 += 64) {
        {
            int rrow = tid >> 2, c0 = (tid & 3) * 16;
            const f16* s = Kh + (size_t)(j0 + rrow) * 64 + c0;
            *(f16x8*)(Bt + rrow * BST + c0) = *(const f16x8*)(s);
            *(f16x8*)(Bt + rrow * BST + c0 + 8) = *(const f16x8*)(s + 8);
        }
        __syncthreads();
        f32x4 acc[2][2] = {{zero, zero}, {zero, zero}};
#pragma unroll
        for (int ks = 0; ks < 2; ++ks) {
            f16x8 b0 = *(const f16x8*)(Bt + (n_off + fr) * BST + ks * 32 + kq);
            f16x8 b1 = *(const f16x8*)(Bt + (n_off + 16 + fr) * BST + ks * 32 + kq);
            acc[0][0] = __builtin_amdgcn_mfma_f32_16x16x32_f16(qu_f[0][ks], b0, acc[0][0], 0, 0, 0);
            acc[0][1] = __builtin_amdgcn_mfma_f32_16x16x32_f16(qu_f[0][ks], b1, acc[0][1], 0, 0, 0);
            acc[1][0] = __builtin_amdgcn_mfma_f32_16x16x32_f16(qu_f[1][ks], b0, acc[1][0], 0, 0, 0);
            acc[1][1] = __builtin_amdgcn_mfma_f32_16x16x32_f16(qu_f[1][ks], b1, acc[1][1], 0, 0, 0);
        }
#pragma unroll
        for (int mt = 0; mt < 2; ++mt)
#pragma unroll
            for (int nt = 0; nt < 2; ++nt)
#pragma unroll
                for (int rr = 0; rr < 4; ++rr) {
                    int m = m_off + mt * 16 + (lane >> 4) * 4 + rr;
                    int c = j0 + n_off + nt * 16 + fr;
                    float sc = ((float)Ssc[m * SST + c] + acc[mt][nt][rr]) * 0.125f;
                    Ssc[m * SST + c] = (f16)sc;
                }
        __syncthreads();
    }

    // ---- phase 4: mask + softmax per row; write attn (f32) and probs back to LDS ----
    float* Ab = attn + (size_t)bh * 1048576;
    const int* MK = mask + ((size_t)b * 1024 + i0) * 1024;
    for (int rr = 0; rr < 16; ++rr) {
        int lr = w * 16 + rr;
        int c0 = lane * 16;
        f16x8 a0 = *(const f16x8*)(Ssc + lr * SST + c0);
        f16x8 a1 = *(const f16x8*)(Ssc + lr * SST + c0 + 8);
        const int* mrow = MK + (size_t)lr * 1024 + c0;
        int4 mk0 = *(const int4*)mrow;
        int4 mk1 = *(const int4*)(mrow + 4);
        int4 mk2 = *(const int4*)(mrow + 8);
        int4 mk3 = *(const int4*)(mrow + 12);
        int mks[16] = {mk0.x, mk0.y, mk0.z, mk0.w, mk1.x, mk1.y, mk1.z, mk1.w,
                       mk2.x, mk2.y, mk2.z, mk2.w, mk3.x, mk3.y, mk3.z, mk3.w};
        float vals[16];
        float mx = -1e30f;
#pragma unroll
        for (int j = 0; j < 16; ++j) {
            float v = (j < 8) ? (float)a0[j] : (float)a1[j - 8];
            if (mks[j] == 0) v = -10000.0f;
            vals[j] = v;
            mx = fmaxf(mx, v);
        }
#pragma unroll
        for (int off = 32; off > 0; off >>= 1) mx = fmaxf(mx, __shfl_xor(mx, off));
        float sum = 0.f;
#pragma unroll
        for (int j = 0; j < 16; ++j) { vals[j] = __expf(vals[j] - mx); sum += vals[j]; }
#pragma unroll
        for (int off = 32; off > 0; off >>= 1) sum += __shfl_xor(sum, off);
        float il = 1.f / sum;
        float* arow = Ab + (size_t)(i0 + lr) * 1024 + c0;
        float4 f0 = {vals[0] * il, vals[1] * il, vals[2] * il, vals[3] * il};
        float4 f1 = {vals[4] * il, vals[5] * il, vals[6] * il, vals[7] * il};
        float4 f2 = {vals[8] * il, vals[9] * il, vals[10] * il, vals[11] * il};
        float4 f3 = {vals[12] * il, vals[13] * il, vals[14] * il, vals[15] * il};
        *(float4*)(arow) = f0;
        *(float4*)(arow + 4) = f1;
        *(float4*)(arow + 8) = f2;
        *(float4*)(arow + 12) = f3;
        f16x8 p0, p1;
#pragma unroll
        for (int j = 0; j < 8; ++j) {
            p0[j] = (f16)(vals[j] * il);
            p1[j] = (f16)(vals[8 + j] * il);
        }
        *(f16x8*)(Ssc + lr * SST + c0) = p0;
        *(f16x8*)(Ssc + lr * SST + c0 + 8) = p1;
    }
    __syncthreads();

    // ---- phase 5: PV = probs @ V ----
    f32x4 acc[2][2] = {{zero, zero}, {zero, zero}};
    for (int j0 = 0; j0 < 1024; j0 += 64) {
        {   // stage V^T: Bt[d][s]
            int srow = tid >> 2, d0 = (tid & 3) * 16;
            const f16* s = Vh + (size_t)(j0 + srow) * 64 + d0;
            f16x8 h0 = *(const f16x8*)(s);
            f16x8 h1 = *(const f16x8*)(s + 8);
#pragma unroll
            for (int j = 0; j < 8; ++j) {
                Bt[(d0 + j) * BST + srow] = h0[j];
                Bt[(d0 + 8 + j) * BST + srow] = h1[j];
            }
        }
        __syncthreads();
#pragma unroll
        for (int ks = 0; ks < 2; ++ks) {
            f16x8 a0 = *(const f16x8*)(Ssc + (m_off + fr) * SST + j0 + ks * 32 + kq);
            f16x8 a1 = *(const f16x8*)(Ssc + (m_off + 16 + fr) * SST + j0 + ks * 32 + kq);
            f16x8 b0 = *(const f16x8*)(Bt + (n_off + fr) * BST + ks * 32 + kq);
            f16x8 b1 = *(const f16x8*)(Bt + (n_off + 16 + fr) * BST + ks * 32 + kq);
            acc[0][0] = __builtin_amdgcn_mfma_f32_16x16x32_f16(a0, b0, acc[0][0], 0, 0, 0);
            acc[0][1] = __builtin_amdgcn_mfma_f32_16x16x32_f16(a0, b1, acc[0][1], 0, 0, 0);
            acc[1][0] = __builtin_amdgcn_mfma_f32_16x16x32_f16(a1, b0, acc[1][0], 0, 0, 0);
            acc[1][1] = __builtin_amdgcn_mfma_f32_16x16x32_f16(a1, b1, acc[1][1], 0, 0, 0);
        }
        __syncthreads();
    }
#pragma unroll
    for (int mt = 0; mt < 2; ++mt)
#pragma unroll
        for (int nt = 0; nt < 2; ++nt)
#pragma unroll
            for (int rr = 0; rr < 4; ++rr) {
                int t = i0 + m_off + mt * 16 + (lane >> 4) * 4 + rr;
                int d = n_off + nt * 16 + fr;
                oh[((size_t)(b * 1024 + t)) * 1024 + h * 64 + d] = (f16)acc[mt][nt][rr];
            }
}

// output = concat @ Wo^T + bo (fp32 out)
__global__ __launch_bounds__(256) void out_gemm(const f16* __restrict__ A,
                                                const f16* __restrict__ W,
                                                const float* __restrict__ bias,
                                                float* __restrict__ out) {
    GEMM_PROLOGUE();
    const int m0 = blockIdx.y * 64;
    const int n0 = blockIdx.x * 64;
    for (int k0 = 0; k0 < 1024; k0 += 32) {
        stage_f16g(A + (size_t)m0 * 1024 + k0, 1024, As);
        stage_f16g(W + (size_t)n0 * 1024 + k0, 1024, Bs);
        __syncthreads();
        mma_step(As, Bs, m_off, n_off, acc);
        __syncthreads();
    }
#pragma unroll
    for (int mt = 0; mt < 2; ++mt)
#pragma unroll
        for (int nt = 0; nt < 2; ++nt)
#pragma unroll
            for (int rr = 0; rr < 4; ++rr) {
                int m = m0 + m_off + mt * 16 + (lane >> 4) * 4 + rr;
                int n = n0 + n_off + nt * 16 + (lane & 15);
                out[(size_t)m * 1024 + n] = acc[mt][nt][rr] + bias[n];
            }
}

extern "C" void kernel_launch(void* const* d_in, const int* in_sizes, int n_in,
                              void* d_out, int out_size, void* d_ws, size_t ws_size,
                              hipStream_t stream) {
    (void)in_sizes; (void)n_in; (void)out_size; (void)ws_size;
    const float* q   = (const float*)d_in[0];
    const float* k   = (const float*)d_in[1];
    const float* v   = (const float*)d_in[2];
    const float* pe  = (const float*)d_in[3];
    const int*   msk = (const int*)d_in[4];
    const float* Wq  = (const float*)d_in[5];
    const float* bq  = (const float*)d_in[6];
    const float* Wk  = (const float*)d_in[7];
    const float* bk  = (const float*)d_in[8];
    const float* Wv  = (const float*)d_in[9];
    const float* bv  = (const float*)d_in[10];
    const float* Wp  = (const float*)d_in[11];
    const float* pbu = (const float*)d_in[12];
    const float* pbv = (const float*)d_in[13];
    const float* Wo  = (const float*)d_in[14];
    const float* bo  = (const float*)d_in[15];

    char* ws = (char*)d_ws;
    f16* cvt = (f16*)(ws + 0);  // 36 MB: q,k,v,pe,Wq,Wk,Wv,Wp,Wo in f16
    f16* qf  = cvt;
    f16* kf  = cvt + 4194304;
    f16* vf  = cvt + 8388608;
    f16* pef = cvt + 12582912;
    f16* Wqf = cvt + 13631488;
    f16* Wkf = cvt + 14680064;
    f16* Wvf = cvt + 15728640;
    f16* Wpf = cvt + 16777216;
    f16* Wof = cvt + 17825792;

    f16* q_u = (f16*)(ws + 37748736);   //  8 MB  [b][h][t][64]
    f16* q_v = (f16*)(ws + 46137344);   //  8 MB
    f16* kh  = (f16*)(ws + 54525952);   //  8 MB
    f16* vh  = (f16*)(ws + 62914560);   //  8 MB
    f16* pp  = (f16*)(ws + 71303168);   //  2 MB  [h][pos][64]
    f16* oh  = (f16*)(ws + 73400320);   //  8 MB  [b][t][h*64+d]

    float* out  = (float*)d_out;
    float* attn = out + 4194304;

    dim3 blk(256);
    cvt_all<<<dim3(1024, 9), blk, 0, stream>>>(q, k, v, pe, Wq, Wk, Wv, Wp, Wo, cvt);
    proj_qkv<<<dim3(16, 64, 3), blk, 0, stream>>>(qf, kf, vf, Wqf, Wkf, Wvf, bq, bk, bv,
                                                  pbu, pbv, q_u, q_v, kh, vh);
    proj_p<<<dim3(16, 16), blk, 0, stream>>>(pef, Wpf, pp);
    fused_attn<<<dim3(16, 64), blk, 0, stream>>>(q_u, q_v, kh, pp, vh, msk, attn, oh);
    out_gemm<<<dim3(16, 64), blk, 0, stream>>>(oh, Wof, bo, out);
}

// Round 2
// 684.838 us; speedup vs baseline: 1.1345x; 1.1345x over previous
//
#include <hip/hip_runtime.h>

typedef _Float16 f16;
typedef __attribute__((ext_vector_type(8))) _Float16 f16x8;
typedef __attribute__((ext_vector_type(4))) float f32x4;

#define LDK 40   // LDS row stride (f16) for 32-wide K staging tiles (proj GEMMs)
#define SST 1032 // score LDS row stride in f16 (2064 B, 16B-aligned)
#define BST 72   // 64x64 B-tile stride in f16 (144 B, 16B-aligned)

// ---- staging helper: tile is 64 rows x 32 K-cols, 256 threads ----
__device__ __forceinline__ void stage_f16g(const f16* __restrict__ src, int ld, f16* dst) {
    int t = threadIdx.x;
    int row = t >> 2;
    int c0 = (t & 3) * 8;
    *(f16x8*)(dst + row * LDK + c0) = *(const f16x8*)(src + (size_t)row * ld + c0);
}

// ---- MFMA core: 4 waves, each computes 32x32 of a 64x64 C tile ----
__device__ __forceinline__ void mma_step(const f16* As, const f16* Bs, int m_off, int n_off,
                                         f32x4 acc[2][2]) {
    int lane = threadIdx.x & 63;
    int r = lane & 15;
    int kq = (lane >> 4) * 8;
    f16x8 a0 = *(const f16x8*)(As + (m_off + r) * LDK + kq);
    f16x8 a1 = *(const f16x8*)(As + (m_off + 16 + r) * LDK + kq);
    f16x8 b0 = *(const f16x8*)(Bs + (n_off + r) * LDK + kq);
    f16x8 b1 = *(const f16x8*)(Bs + (n_off + 16 + r) * LDK + kq);
    acc[0][0] = __builtin_amdgcn_mfma_f32_16x16x32_f16(a0, b0, acc[0][0], 0, 0, 0);
    acc[0][1] = __builtin_amdgcn_mfma_f32_16x16x32_f16(a0, b1, acc[0][1], 0, 0, 0);
    acc[1][0] = __builtin_amdgcn_mfma_f32_16x16x32_f16(a1, b0, acc[1][0], 0, 0, 0);
    acc[1][1] = __builtin_amdgcn_mfma_f32_16x16x32_f16(a1, b1, acc[1][1], 0, 0, 0);
}

#define GEMM_PROLOGUE()                                         \
    __shared__ __align__(16) f16 As[64 * LDK];                  \
    __shared__ __align__(16) f16 Bs[64 * LDK];                  \
    const int w = threadIdx.x >> 6;                             \
    const int m_off = (w & 1) * 32, n_off = (w >> 1) * 32;      \
    const int lane = threadIdx.x & 63;                          \
    f32x4 zero = {0.f, 0.f, 0.f, 0.f};                          \
    f32x4 acc[2][2] = {{zero, zero}, {zero, zero}};

// ---- convert all fp32 inputs/weights to f16 once ----
__global__ __launch_bounds__(256) void cvt_all(
    const float* __restrict__ q, const float* __restrict__ k, const float* __restrict__ v,
    const float* __restrict__ pe, const float* __restrict__ Wq, const float* __restrict__ Wk,
    const float* __restrict__ Wv, const float* __restrict__ Wp, const float* __restrict__ Wo,
    f16* __restrict__ dst) {
    const int seg = blockIdx.y;
    const float* srcs[9] = {q, k, v, pe, Wq, Wk, Wv, Wp, Wo};
    const int sz = (seg < 3) ? 4194304 : 1048576;
    const size_t off = (seg < 3) ? (size_t)seg * 4194304
                                 : (size_t)12582912 + (size_t)(seg - 3) * 1048576;
    const size_t i0 = ((size_t)blockIdx.x * 256 + threadIdx.x) * 16;
    if (i0 >= (size_t)sz) return;
    const float* s = srcs[seg] + i0;
    f16* d = dst + off + i0;
#pragma unroll
    for (int half = 0; half < 2; ++half) {
        float4 u = *(const float4*)(s + half * 8);
        float4 w = *(const float4*)(s + half * 8 + 4);
        f16x8 h;
        h[0] = (f16)u.x; h[1] = (f16)u.y; h[2] = (f16)u.z; h[3] = (f16)u.w;
        h[4] = (f16)w.x; h[5] = (f16)w.y; h[6] = (f16)w.z; h[7] = (f16)w.w;
        *(f16x8*)(d + half * 8) = h;
    }
}

// ---- batched Q/K/V projection: grid.z selects which ----
__global__ __launch_bounds__(256) void proj_qkv(
    const f16* __restrict__ qf, const f16* __restrict__ kf, const f16* __restrict__ vf,
    const f16* __restrict__ Wqf, const f16* __restrict__ Wkf, const f16* __restrict__ Wvf,
    const float* __restrict__ bq, const float* __restrict__ bk, const float* __restrict__ bv,
    const float* __restrict__ pbu, const float* __restrict__ pbv,
    f16* __restrict__ q_u, f16* __restrict__ q_v, f16* __restrict__ kh,
    f16* __restrict__ vh) {
    GEMM_PROLOGUE();
    const int z = blockIdx.z;
    const f16* A = (z == 0) ? qf : (z == 1) ? kf : vf;
    const f16* W = (z == 0) ? Wqf : (z == 1) ? Wkf : Wvf;
    const float* bias = (z == 0) ? bq : (z == 1) ? bk : bv;
    const int m0 = blockIdx.y * 64, n0 = blockIdx.x * 64;
    for (int k0 = 0; k0 < 1024; k0 += 32) {
        stage_f16g(A + (size_t)m0 * 1024 + k0, 1024, As);
        stage_f16g(W + (size_t)n0 * 1024 + k0, 1024, Bs);
        __syncthreads();
        mma_step(As, Bs, m_off, n_off, acc);
        __syncthreads();
    }
#pragma unroll
    for (int mt = 0; mt < 2; ++mt)
#pragma unroll
        for (int nt = 0; nt < 2; ++nt)
#pragma unroll
            for (int rr = 0; rr < 4; ++rr) {
                int m = m0 + m_off + mt * 16 + (lane >> 4) * 4 + rr;
                int n = n0 + n_off + nt * 16 + (lane & 15);
                float base = acc[mt][nt][rr] + bias[n];
                int b = m >> 10, t = m & 1023, h = n >> 6, d = n & 63;
                size_t idx = ((size_t)((b * 16 + h) * 1024 + t)) * 64 + d;
                if (z == 0) {
                    q_u[idx] = (f16)(base + pbu[n]);
                    q_v[idx] = (f16)(base + pbv[n]);
                } else if (z == 1) {
                    kh[idx] = (f16)base;
                } else {
                    vh[idx] = (f16)base;
                }
            }
}

// ---- P projection (no bias): pp[h][pos][64] ----
__global__ __launch_bounds__(256) void proj_p(const f16* __restrict__ A,
                                              const f16* __restrict__ W,
                                              f16* __restrict__ o1) {
    GEMM_PROLOGUE();
    const int m0 = blockIdx.y * 64;
    const int n0 = blockIdx.x * 64;
    for (int k0 = 0; k0 < 1024; k0 += 32) {
        stage_f16g(A + (size_t)m0 * 1024 + k0, 1024, As);
        stage_f16g(W + (size_t)n0 * 1024 + k0, 1024, Bs);
        __syncthreads();
        mma_step(As, Bs, m_off, n_off, acc);
        __syncthreads();
    }
#pragma unroll
    for (int mt = 0; mt < 2; ++mt)
#pragma unroll
        for (int nt = 0; nt < 2; ++nt)
#pragma unroll
            for (int rr = 0; rr < 4; ++rr) {
                int m = m0 + m_off + mt * 16 + (lane >> 4) * 4 + rr;
                int n = n0 + n_off + nt * 16 + (lane & 15);
                int h = n >> 6, d = n & 63;
                o1[((size_t)h * 1024 + m) * 64 + d] = (f16)acc[mt][nt][rr];
            }
}

// ---- V transpose: vh[bh][s][d] -> vT[bh][d][s] (one-time, 16 MB traffic) ----
__global__ __launch_bounds__(256) void transpose_v(const f16* __restrict__ vh,
                                                   f16* __restrict__ vT) {
    __shared__ __align__(16) f16 T[64 * BST];
    const int bh = blockIdx.y;
    const int j0 = blockIdx.x * 64;
    const int t = threadIdx.x;
    const int s = t >> 2, c0 = (t & 3) * 16;
    const f16* src = vh + (size_t)bh * 65536 + (size_t)(j0 + s) * 64;
    *(f16x8*)(T + s * BST + c0) = *(const f16x8*)(src + c0);
    *(f16x8*)(T + s * BST + c0 + 8) = *(const f16x8*)(src + c0 + 8);
    __syncthreads();
    const int d = t >> 2;
    f16x8 o0, o1;
#pragma unroll
    for (int j = 0; j < 8; ++j) {
        o0[j] = T[(c0 + j) * BST + d];
        o1[j] = T[(c0 + 8 + j) * BST + d];
    }
    f16* dst = vT + (size_t)bh * 65536 + (size_t)d * 1024 + j0 + c0;
    *(f16x8*)(dst) = o0;
    *(f16x8*)(dst + 8) = o1;
}

// ---- fused attention v2: 32-row tiles, 2 blocks/CU ----
// grid (32 row-tiles, 64 bh), 256 threads. Scores 32 x 1024 in LDS (64.5 KB).
// 4 waves: m_off=(w&1)*16 picks 16-row group, n_off=(w>>1)*32 picks 32-col group.
__global__ __launch_bounds__(256, 2) void fused_attn(
    const f16* __restrict__ q_u, const f16* __restrict__ q_v,
    const f16* __restrict__ kh, const f16* __restrict__ pp,
    const f16* __restrict__ vT, const int* __restrict__ mask,
    float* __restrict__ attn, f16* __restrict__ oh) {
    __shared__ __align__(16) f16 Ssc[32 * SST];   // 64.5 KB score tile
    __shared__ __align__(16) f16 Bt[64 * BST];    // 9 KB B staging (pp / kh / vT)
    __shared__ __align__(16) f16 rawX[1024];      // raw BD row i0+32 (rel_shift wrap)
    __shared__ __align__(16) f16 qxrow[64];       // q_v row i0+32

    const int bh = blockIdx.y;
    const int b = bh >> 4, h = bh & 15;
    const int i0 = blockIdx.x * 32;
    const int tid = threadIdx.x;
    const int w = tid >> 6;
    const int lane = tid & 63;
    const int m_off = (w & 1) * 16, n_off = (w >> 1) * 32;
    const int fr = lane & 15;
    const int kq = (lane >> 4) * 8;
    const f32x4 zero = {0.f, 0.f, 0.f, 0.f};

    const f16* Qu = q_u + (size_t)bh * 65536;
    const f16* Qv = q_v + (size_t)bh * 65536;
    const f16* Kh = kh + (size_t)bh * 65536;
    const f16* Pp = pp + (size_t)h * 65536;
    const f16* Vt = vT + (size_t)bh * 65536;

    // A-fragments (q_u, q_v) in registers: [ks]
    f16x8 qu_f[2], qv_f[2];
#pragma unroll
    for (int ks = 0; ks < 2; ++ks) {
        size_t off = (size_t)(i0 + m_off + fr) * 64 + ks * 32 + kq;
        qu_f[ks] = *(const f16x8*)(Qu + off);
        qv_f[ks] = *(const f16x8*)(Qv + off);
    }
    if (i0 + 32 < 1024 && tid < 8)
        *(f16x8*)(qxrow + tid * 8) = *(const f16x8*)(Qv + (size_t)(i0 + 32) * 64 + tid * 8);

    // ---- phase 1: raw BD = q_v @ pp^T -> Ssc (f16) ----
    const int srow = tid >> 2, sc0 = (tid & 3) * 16;
    for (int j0 = 0; j0 < 1024; j0 += 64) {
        {
            const f16* s = Pp + (size_t)(j0 + srow) * 64 + sc0;
            *(f16x8*)(Bt + srow * BST + sc0) = *(const f16x8*)(s);
            *(f16x8*)(Bt + srow * BST + sc0 + 8) = *(const f16x8*)(s + 8);
        }
        __syncthreads();
        f32x4 acc[2] = {zero, zero};
#pragma unroll
        for (int ks = 0; ks < 2; ++ks) {
            f16x8 b0 = *(const f16x8*)(Bt + (n_off + fr) * BST + ks * 32 + kq);
            f16x8 b1 = *(const f16x8*)(Bt + (n_off + 16 + fr) * BST + ks * 32 + kq);
            acc[0] = __builtin_amdgcn_mfma_f32_16x16x32_f16(qv_f[ks], b0, acc[0], 0, 0, 0);
            acc[1] = __builtin_amdgcn_mfma_f32_16x16x32_f16(qv_f[ks], b1, acc[1], 0, 0, 0);
        }
#pragma unroll
        for (int nt = 0; nt < 2; ++nt)
#pragma unroll
            for (int rr = 0; rr < 4; ++rr) {
                int m = m_off + (lane >> 4) * 4 + rr;
                int c = j0 + n_off + nt * 16 + fr;
                Ssc[m * SST + c] = (f16)acc[nt][rr];
            }
        __syncthreads();
    }

    // ---- phase 1b: rawX[p] = q_v[i0+32] . pp[p] ----
    if (i0 + 32 < 1024) {
        int p = tid * 4;
#pragma unroll
        for (int pi = 0; pi < 4; ++pi) {
            const f16* pr = Pp + (size_t)(p + pi) * 64;
            float sacc = 0.f;
#pragma unroll
            for (int c = 0; c < 64; c += 8) {
                f16x8 pv = *(const f16x8*)(pr + c);
                f16x8 qv8 = *(const f16x8*)(qxrow + c);
#pragma unroll
                for (int j = 0; j < 8; ++j) sacc += (float)pv[j] * (float)qv8[j];
            }
            rawX[p + pi] = (f16)sacc;
        }
    }
    __syncthreads();

    // ---- phase 2: rel_shift fully in registers: read 8 rows/wave, 1 barrier, write ----
    // shifted[r][s] = raw[r][s+1023-r] (s<=r) | 0 (s==r+1) | raw[r+1][s-r-2] (s>=r+2)
    {
        const int s0 = lane * 16;
        f16 tmp[8][16];
#pragma unroll
        for (int rr2 = 0; rr2 < 8; ++rr2) {
            int lr = w * 8 + rr2;
            int r = i0 + lr;
#pragma unroll
            for (int j = 0; j < 16; ++j) {
                int s = s0 + j;
                f16 val;
                if (s <= r) val = Ssc[lr * SST + (s + 1023 - r)];
                else if (s == r + 1) val = (f16)0.f;
                else val = (lr == 31) ? rawX[s - r - 2] : Ssc[(lr + 1) * SST + (s - r - 2)];
                tmp[rr2][j] = val;
            }
        }
        __syncthreads();
#pragma unroll
        for (int rr2 = 0; rr2 < 8; ++rr2) {
            int lr = w * 8 + rr2;
            f16x8 o0, o1;
#pragma unroll
            for (int j = 0; j < 8; ++j) { o0[j] = tmp[rr2][j]; o1[j] = tmp[rr2][8 + j]; }
            *(f16x8*)(Ssc + lr * SST + s0) = o0;
            *(f16x8*)(Ssc + lr * SST + s0 + 8) = o1;
        }
    }
    __syncthreads();

    // ---- phase 3: scores = (shiftedBD + q_u @ kh^T) * 0.125, in place ----
    for (int j0 = 0; j0 < 1024; j0 += 64) {
        {
            const f16* s = Kh + (size_t)(j0 + srow) * 64 + sc0;
            *(f16x8*)(Bt + srow * BST + sc0) = *(const f16x8*)(s);
            *(f16x8*)(Bt + srow * BST + sc0 + 8) = *(const f16x8*)(s + 8);
        }
        __syncthreads();
        f32x4 acc[2] = {zero, zero};
#pragma unroll
        for (int ks = 0; ks < 2; ++ks) {
            f16x8 b0 = *(const f16x8*)(Bt + (n_off + fr) * BST + ks * 32 + kq);
            f16x8 b1 = *(const f16x8*)(Bt + (n_off + 16 + fr) * BST + ks * 32 + kq);
            acc[0] = __builtin_amdgcn_mfma_f32_16x16x32_f16(qu_f[ks], b0, acc[0], 0, 0, 0);
            acc[1] = __builtin_amdgcn_mfma_f32_16x16x32_f16(qu_f[ks], b1, acc[1], 0, 0, 0);
        }
#pragma unroll
        for (int nt = 0; nt < 2; ++nt)
#pragma unroll
            for (int rr = 0; rr < 4; ++rr) {
                int m = m_off + (lane >> 4) * 4 + rr;
                int c = j0 + n_off + nt * 16 + fr;
                float sc = ((float)Ssc[m * SST + c] + acc[nt][rr]) * 0.125f;
                Ssc[m * SST + c] = (f16)sc;
            }
        __syncthreads();
    }

    // ---- phase 4: mask + softmax per row; write attn (f32), probs back to LDS ----
    float* Ab = attn + (size_t)bh * 1048576;
    const int* MK = mask + ((size_t)b * 1024 + i0) * 1024;
    for (int rr = 0; rr < 8; ++rr) {
        int lr = w * 8 + rr;
        int c0 = lane * 16;
        f16x8 a0 = *(const f16x8*)(Ssc + lr * SST + c0);
        f16x8 a1 = *(const f16x8*)(Ssc + lr * SST + c0 + 8);
        const int* mrow = MK + (size_t)lr * 1024 + c0;
        int4 mk0 = *(const int4*)mrow;
        int4 mk1 = *(const int4*)(mrow + 4);
        int4 mk2 = *(const int4*)(mrow + 8);
        int4 mk3 = *(const int4*)(mrow + 12);
        int mks[16] = {mk0.x, mk0.y, mk0.z, mk0.w, mk1.x, mk1.y, mk1.z, mk1.w,
                       mk2.x, mk2.y, mk2.z, mk2.w, mk3.x, mk3.y, mk3.z, mk3.w};
        float vals[16];
        float mx = -1e30f;
#pragma unroll
        for (int j = 0; j < 16; ++j) {
            float v = (j < 8) ? (float)a0[j] : (float)a1[j - 8];
            if (mks[j] == 0) v = -10000.0f;
            vals[j] = v;
            mx = fmaxf(mx, v);
        }
#pragma unroll
        for (int off = 32; off > 0; off >>= 1) mx = fmaxf(mx, __shfl_xor(mx, off));
        float sum = 0.f;
#pragma unroll
        for (int j = 0; j < 16; ++j) { vals[j] = __expf(vals[j] - mx); sum += vals[j]; }
#pragma unroll
        for (int off = 32; off > 0; off >>= 1) sum += __shfl_xor(sum, off);
        float il = 1.f / sum;
        float* arow = Ab + (size_t)(i0 + lr) * 1024 + c0;
        float4 f0 = {vals[0] * il, vals[1] * il, vals[2] * il, vals[3] * il};
        float4 f1 = {vals[4] * il, vals[5] * il, vals[6] * il, vals[7] * il};
        float4 f2 = {vals[8] * il, vals[9] * il, vals[10] * il, vals[11] * il};
        float4 f3 = {vals[12] * il, vals[13] * il, vals[14] * il, vals[15] * il};
        *(float4*)(arow) = f0;
        *(float4*)(arow + 4) = f1;
        *(float4*)(arow + 8) = f2;
        *(float4*)(arow + 12) = f3;
        f16x8 p0, p1;
#pragma unroll
        for (int j = 0; j < 8; ++j) {
            p0[j] = (f16)(vals[j] * il);
            p1[j] = (f16)(vals[8 + j] * il);
        }
        *(f16x8*)(Ssc + lr * SST + c0) = p0;
        *(f16x8*)(Ssc + lr * SST + c0 + 8) = p1;
    }

    // ---- phase 5: PV = probs @ V (vT staged coalesced, no scatter) ----
    f32x4 accp[2] = {zero, zero};
    for (int j0 = 0; j0 < 1024; j0 += 64) {
        {
            const f16* s = Vt + (size_t)srow * 1024 + j0 + sc0;
            *(f16x8*)(Bt + srow * BST + sc0) = *(const f16x8*)(s);
            *(f16x8*)(Bt + srow * BST + sc0 + 8) = *(const f16x8*)(s + 8);
        }
        __syncthreads();
#pragma unroll
        for (int ks = 0; ks < 2; ++ks) {
            f16x8 a0 = *(const f16x8*)(Ssc + (m_off + fr) * SST + j0 + ks * 32 + kq);
            f16x8 b0 = *(const f16x8*)(Bt + (n_off + fr) * BST + ks * 32 + kq);
            f16x8 b1 = *(const f16x8*)(Bt + (n_off + 16 + fr) * BST + ks * 32 + kq);
            accp[0] = __builtin_amdgcn_mfma_f32_16x16x32_f16(a0, b0, accp[0], 0, 0, 0);
            accp[1] = __builtin_amdgcn_mfma_f32_16x16x32_f16(a0, b1, accp[1], 0, 0, 0);
        }
        __syncthreads();
    }
#pragma unroll
    for (int nt = 0; nt < 2; ++nt)
#pragma unroll
        for (int rr = 0; rr < 4; ++rr) {
            int t = i0 + m_off + (lane >> 4) * 4 + rr;
            int d = n_off + nt * 16 + fr;
            oh[((size_t)(b * 1024 + t)) * 1024 + h * 64 + d] = (f16)accp[nt][rr];
        }
}

// output = concat @ Wo^T + bo (fp32 out)
__global__ __launch_bounds__(256) void out_gemm(const f16* __restrict__ A,
                                                const f16* __restrict__ W,
                                                const float* __restrict__ bias,
                                                float* __restrict__ out) {
    GEMM_PROLOGUE();
    const int m0 = blockIdx.y * 64;
    const int n0 = blockIdx.x * 64;
    for (int k0 = 0; k0 < 1024; k0 += 32) {
        stage_f16g(A + (size_t)m0 * 1024 + k0, 1024, As);
        stage_f16g(W + (size_t)n0 * 1024 + k0, 1024, Bs);
        __syncthreads();
        mma_step(As, Bs, m_off, n_off, acc);
        __syncthreads();
    }
#pragma unroll
    for (int mt = 0; mt < 2; ++mt)
#pragma unroll
        for (int nt = 0; nt < 2; ++nt)
#pragma unroll
            for (int rr = 0; rr < 4; ++rr) {
                int m = m0 + m_off + mt * 16 + (lane >> 4) * 4 + rr;
                int n = n0 + n_off + nt * 16 + (lane & 15);
                out[(size_t)m * 1024 + n] = acc[mt][nt][rr] + bias[n];
            }
}

extern "C" void kernel_launch(void* const* d_in, const int* in_sizes, int n_in,
                              void* d_out, int out_size, void* d_ws, size_t ws_size,
                              hipStream_t stream) {
    (void)in_sizes; (void)n_in; (void)out_size; (void)ws_size;
    const float* q   = (const float*)d_in[0];
    const float* k   = (const float*)d_in[1];
    const float* v   = (const float*)d_in[2];
    const float* pe  = (const float*)d_in[3];
    const int*   msk = (const int*)d_in[4];
    const float* Wq  = (const float*)d_in[5];
    const float* bq  = (const float*)d_in[6];
    const float* Wk  = (const float*)d_in[7];
    const float* bk  = (const float*)d_in[8];
    const float* Wv  = (const float*)d_in[9];
    const float* bv  = (const float*)d_in[10];
    const float* Wp  = (const float*)d_in[11];
    const float* pbu = (const float*)d_in[12];
    const float* pbv = (const float*)d_in[13];
    const float* Wo  = (const float*)d_in[14];
    const float* bo  = (const float*)d_in[15];

    char* ws = (char*)d_ws;
    f16* cvt = (f16*)(ws + 0);  // 36 MB: q,k,v,pe,Wq,Wk,Wv,Wp,Wo in f16
    f16* qf  = cvt;
    f16* kf  = cvt + 4194304;
    f16* vf  = cvt + 8388608;
    f16* pef = cvt + 12582912;
    f16* Wqf = cvt + 13631488;
    f16* Wkf = cvt + 14680064;
    f16* Wvf = cvt + 15728640;
    f16* Wpf = cvt + 16777216;
    f16* Wof = cvt + 17825792;

    f16* q_u = (f16*)(ws + 37748736);   //  8 MB  [b][h][t][64]
    f16* q_v = (f16*)(ws + 46137344);   //  8 MB
    f16* kh  = (f16*)(ws + 54525952);   //  8 MB
    f16* vh  = (f16*)(ws + 62914560);   //  8 MB
    f16* pp  = (f16*)(ws + 71303168);   //  2 MB  [h][pos][64]
    f16* oh  = (f16*)(ws + 73400320);   //  8 MB  [b][t][h*64+d]
    f16* vT  = (f16*)(ws + 81788928);   //  8 MB  [b][h][d][s]

    float* out  = (float*)d_out;
    float* attn = out + 4194304;

    dim3 blk(256);
    cvt_all<<<dim3(1024, 9), blk, 0, stream>>>(q, k, v, pe, Wq, Wk, Wv, Wp, Wo, cvt);
    proj_qkv<<<dim3(16, 64, 3), blk, 0, stream>>>(qf, kf, vf, Wqf, Wkf, Wvf, bq, bk, bv,
                                                  pbu, pbv, q_u, q_v, kh, vh);
    proj_p<<<dim3(16, 16), blk, 0, stream>>>(pef, Wpf, pp);
    transpose_v<<<dim3(16, 64), blk, 0, stream>>>(vh, vT);
    fused_attn<<<dim3(32, 64), blk, 0, stream>>>(q_u, q_v, kh, pp, vT, msk, attn, oh);
    out_gemm<<<dim3(16, 64), blk, 0, stream>>>(oh, Wof, bo, out);
}

// Round 3
// 602.213 us; speedup vs baseline: 1.2901x; 1.1372x over previous
//
#include <hip/hip_runtime.h>

typedef _Float16 f16;
typedef __attribute__((ext_vector_type(8))) _Float16 f16x8;
typedef __attribute__((ext_vector_type(4))) float f32x4;

#define LDK 40   // LDS row stride (f16) for 32-wide K staging tiles (proj GEMMs)
#define SST 1032 // score LDS row stride in f16 (2064 B, 16B-aligned)
#define BST 72   // 64x64 B-tile stride in f16 (144 B, 16B-aligned)

// ---- staging helpers (64 rows x 32 K-cols tile, 256 threads) ----
__device__ __forceinline__ f16x8 ld_half(const f16* __restrict__ src, int ld) {
    int t = threadIdx.x;
    int row = t >> 2;
    int c0 = (t & 3) * 8;
    return *(const f16x8*)(src + (size_t)row * ld + c0);
}
__device__ __forceinline__ void st_half(f16* dst, f16x8 v) {
    int t = threadIdx.x;
    int row = t >> 2;
    int c0 = (t & 3) * 8;
    *(f16x8*)(dst + row * LDK + c0) = v;
}

// ---- MFMA core: 4 waves, each computes 32x32 of a 64x64 C tile ----
__device__ __forceinline__ void mma_step(const f16* As, const f16* Bs, int m_off, int n_off,
                                         f32x4 acc[2][2]) {
    int lane = threadIdx.x & 63;
    int r = lane & 15;
    int kq = (lane >> 4) * 8;
    f16x8 a0 = *(const f16x8*)(As + (m_off + r) * LDK + kq);
    f16x8 a1 = *(const f16x8*)(As + (m_off + 16 + r) * LDK + kq);
    f16x8 b0 = *(const f16x8*)(Bs + (n_off + r) * LDK + kq);
    f16x8 b1 = *(const f16x8*)(Bs + (n_off + 16 + r) * LDK + kq);
    acc[0][0] = __builtin_amdgcn_mfma_f32_16x16x32_f16(a0, b0, acc[0][0], 0, 0, 0);
    acc[0][1] = __builtin_amdgcn_mfma_f32_16x16x32_f16(a0, b1, acc[0][1], 0, 0, 0);
    acc[1][0] = __builtin_amdgcn_mfma_f32_16x16x32_f16(a1, b0, acc[1][0], 0, 0, 0);
    acc[1][1] = __builtin_amdgcn_mfma_f32_16x16x32_f16(a1, b1, acc[1][1], 0, 0, 0);
}

#define GEMM_PROLOGUE()                                         \
    __shared__ __align__(16) f16 As[64 * LDK];                  \
    __shared__ __align__(16) f16 Bs[64 * LDK];                  \
    const int w = threadIdx.x >> 6;                             \
    const int m_off = (w & 1) * 32, n_off = (w >> 1) * 32;      \
    const int lane = threadIdx.x & 63;                          \
    f32x4 zero = {0.f, 0.f, 0.f, 0.f};                          \
    f32x4 acc[2][2] = {{zero, zero}, {zero, zero}};

// prefetch-double-buffered 64x64 GEMM k-loop over K=1024
#define GEMM_KLOOP(Abase, Wbase)                                        \
    {                                                                   \
        f16x8 ra = ld_half((Abase), 1024);                              \
        f16x8 rb = ld_half((Wbase), 1024);                              \
        for (int k0 = 0; k0 < 1024; k0 += 32) {                         \
            st_half(As, ra);                                            \
            st_half(Bs, rb);                                            \
            __syncthreads();                                            \
            if (k0 + 32 < 1024) {                                       \
                ra = ld_half((Abase) + k0 + 32, 1024);                  \
                rb = ld_half((Wbase) + k0 + 32, 1024);                  \
            }                                                           \
            mma_step(As, Bs, m_off, n_off, acc);                        \
            __syncthreads();                                            \
        }                                                               \
    }

// ---- convert all fp32 inputs/weights to f16 once ----
__global__ __launch_bounds__(256) void cvt_all(
    const float* __restrict__ q, const float* __restrict__ k, const float* __restrict__ v,
    const float* __restrict__ pe, const float* __restrict__ Wq, const float* __restrict__ Wk,
    const float* __restrict__ Wv, const float* __restrict__ Wp, const float* __restrict__ Wo,
    f16* __restrict__ dst) {
    const int seg = blockIdx.y;
    const float* srcs[9] = {q, k, v, pe, Wq, Wk, Wv, Wp, Wo};
    const int sz = (seg < 3) ? 4194304 : 1048576;
    const size_t off = (seg < 3) ? (size_t)seg * 4194304
                                 : (size_t)12582912 + (size_t)(seg - 3) * 1048576;
    const size_t i0 = ((size_t)blockIdx.x * 256 + threadIdx.x) * 16;
    if (i0 >= (size_t)sz) return;
    const float* s = srcs[seg] + i0;
    f16* d = dst + off + i0;
#pragma unroll
    for (int half = 0; half < 2; ++half) {
        float4 u = *(const float4*)(s + half * 8);
        float4 w = *(const float4*)(s + half * 8 + 4);
        f16x8 h;
        h[0] = (f16)u.x; h[1] = (f16)u.y; h[2] = (f16)u.z; h[3] = (f16)u.w;
        h[4] = (f16)w.x; h[5] = (f16)w.y; h[6] = (f16)w.z; h[7] = (f16)w.w;
        *(f16x8*)(d + half * 8) = h;
    }
}

// ---- batched Q/K/V projection: grid.z selects which ----
__global__ __launch_bounds__(256) void proj_qkv(
    const f16* __restrict__ qf, const f16* __restrict__ kf, const f16* __restrict__ vf,
    const f16* __restrict__ Wqf, const f16* __restrict__ Wkf, const f16* __restrict__ Wvf,
    const float* __restrict__ bq, const float* __restrict__ bk, const float* __restrict__ bv,
    const float* __restrict__ pbu, const float* __restrict__ pbv,
    f16* __restrict__ q_u, f16* __restrict__ q_v, f16* __restrict__ kh,
    f16* __restrict__ vh) {
    GEMM_PROLOGUE();
    const int z = blockIdx.z;
    const f16* A = (z == 0) ? qf : (z == 1) ? kf : vf;
    const f16* W = (z == 0) ? Wqf : (z == 1) ? Wkf : Wvf;
    const float* bias = (z == 0) ? bq : (z == 1) ? bk : bv;
    const int m0 = blockIdx.y * 64, n0 = blockIdx.x * 64;
    GEMM_KLOOP(A + (size_t)m0 * 1024, W + (size_t)n0 * 1024);
#pragma unroll
    for (int mt = 0; mt < 2; ++mt)
#pragma unroll
        for (int nt = 0; nt < 2; ++nt)
#pragma unroll
            for (int rr = 0; rr < 4; ++rr) {
                int m = m0 + m_off + mt * 16 + (lane >> 4) * 4 + rr;
                int n = n0 + n_off + nt * 16 + (lane & 15);
                float base = acc[mt][nt][rr] + bias[n];
                int b = m >> 10, t = m & 1023, h = n >> 6, d = n & 63;
                size_t idx = ((size_t)((b * 16 + h) * 1024 + t)) * 64 + d;
                if (z == 0) {
                    q_u[idx] = (f16)(base + pbu[n]);
                    q_v[idx] = (f16)(base + pbv[n]);
                } else if (z == 1) {
                    kh[idx] = (f16)base;
                } else {
                    vh[idx] = (f16)base;
                }
            }
}

// ---- P projection (no bias): pp[h][pos][64] ----
__global__ __launch_bounds__(256) void proj_p(const f16* __restrict__ A,
                                              const f16* __restrict__ W,
                                              f16* __restrict__ o1) {
    GEMM_PROLOGUE();
    const int m0 = blockIdx.y * 64;
    const int n0 = blockIdx.x * 64;
    GEMM_KLOOP(A + (size_t)m0 * 1024, W + (size_t)n0 * 1024);
#pragma unroll
    for (int mt = 0; mt < 2; ++mt)
#pragma unroll
        for (int nt = 0; nt < 2; ++nt)
#pragma unroll
            for (int rr = 0; rr < 4; ++rr) {
                int m = m0 + m_off + mt * 16 + (lane >> 4) * 4 + rr;
                int n = n0 + n_off + nt * 16 + (lane & 15);
                int h = n >> 6, d = n & 63;
                o1[((size_t)h * 1024 + m) * 64 + d] = (f16)acc[mt][nt][rr];
            }
}

// ---- V transpose: vh[bh][s][d] -> vT[bh][d][s] ----
__global__ __launch_bounds__(256) void transpose_v(const f16* __restrict__ vh,
                                                   f16* __restrict__ vT) {
    __shared__ __align__(16) f16 T[64 * BST];
    const int bh = blockIdx.y;
    const int j0 = blockIdx.x * 64;
    const int t = threadIdx.x;
    const int s = t >> 2, c0 = (t & 3) * 16;
    const f16* src = vh + (size_t)bh * 65536 + (size_t)(j0 + s) * 64;
    *(f16x8*)(T + s * BST + c0) = *(const f16x8*)(src + c0);
    *(f16x8*)(T + s * BST + c0 + 8) = *(const f16x8*)(src + c0 + 8);
    __syncthreads();
    const int d = t >> 2;
    f16x8 o0, o1;
#pragma unroll
    for (int j = 0; j < 8; ++j) {
        o0[j] = T[(c0 + j) * BST + d];
        o1[j] = T[(c0 + 8 + j) * BST + d];
    }
    f16* dst = vT + (size_t)bh * 65536 + (size_t)d * 1024 + j0 + c0;
    *(f16x8*)(dst) = o0;
    *(f16x8*)(dst + 8) = o1;
}

// ---- fused attention v3: scatter-shift epilogue, conflict-free softmax,
//      reg-prefetched staging. grid (32 row-tiles, 64 bh), 2 blocks/CU.
__global__ __launch_bounds__(256, 2) void fused_attn(
    const f16* __restrict__ q_u, const f16* __restrict__ q_v,
    const f16* __restrict__ kh, const f16* __restrict__ pp,
    const f16* __restrict__ vT, const int* __restrict__ mask,
    float* __restrict__ attn, f16* __restrict__ oh) {
    __shared__ __align__(16) f16 Ssc[32 * SST];   // 64.5 KB score tile
    __shared__ __align__(16) f16 Bt[64 * BST];    // 9 KB B staging (pp / kh / vT)
    __shared__ __align__(16) f16 qxrow[64];       // q_v row i0+32

    const int bh = blockIdx.y;
    const int b = bh >> 4, h = bh & 15;
    const int i0 = blockIdx.x * 32;
    const int tid = threadIdx.x;
    const int w = tid >> 6;
    const int lane = tid & 63;
    const int m_off = (w & 1) * 16, n_off = (w >> 1) * 32;
    const int fr = lane & 15;
    const int kq = (lane >> 4) * 8;
    const f32x4 zero = {0.f, 0.f, 0.f, 0.f};

    const f16* Qu = q_u + (size_t)bh * 65536;
    const f16* Qv = q_v + (size_t)bh * 65536;
    const f16* Kh = kh + (size_t)bh * 65536;
    const f16* Pp = pp + (size_t)h * 65536;
    const f16* Vt = vT + (size_t)bh * 65536;

    // A-fragments (q_u, q_v) in registers
    f16x8 qu_f[2], qv_f[2];
#pragma unroll
    for (int ks = 0; ks < 2; ++ks) {
        size_t off = (size_t)(i0 + m_off + fr) * 64 + ks * 32 + kq;
        qu_f[ks] = *(const f16x8*)(Qu + off);
        qv_f[ks] = *(const f16x8*)(Qv + off);
    }
    if (i0 + 32 < 1024 && tid < 8)
        *(f16x8*)(qxrow + tid * 8) = *(const f16x8*)(Qv + (size_t)(i0 + 32) * 64 + tid * 8);

    const int srow = tid >> 2, sc0 = (tid & 3) * 16;

    // ---- phase 1: raw BD = q_v @ pp^T, epilogue scatters DIRECTLY to shifted pos ----
    // raw[r][p]: if p+r>=1023 -> Ssc[m][p+r-1023]; else (m>0) -> Ssc[m-1][p+r+1]
    {
        f16x8 pf0, pf1;
        {
            const f16* s = Pp + (size_t)srow * 64 + sc0;
            pf0 = *(const f16x8*)(s);
            pf1 = *(const f16x8*)(s + 8);
        }
        for (int j0 = 0; j0 < 1024; j0 += 64) {
            *(f16x8*)(Bt + srow * BST + sc0) = pf0;
            *(f16x8*)(Bt + srow * BST + sc0 + 8) = pf1;
            __syncthreads();
            if (j0 + 64 < 1024) {
                const f16* s = Pp + (size_t)(j0 + 64 + srow) * 64 + sc0;
                pf0 = *(const f16x8*)(s);
                pf1 = *(const f16x8*)(s + 8);
            }
            f32x4 acc[2] = {zero, zero};
#pragma unroll
            for (int ks = 0; ks < 2; ++ks) {
                f16x8 b0 = *(const f16x8*)(Bt + (n_off + fr) * BST + ks * 32 + kq);
                f16x8 b1 = *(const f16x8*)(Bt + (n_off + 16 + fr) * BST + ks * 32 + kq);
                acc[0] = __builtin_amdgcn_mfma_f32_16x16x32_f16(qv_f[ks], b0, acc[0], 0, 0, 0);
                acc[1] = __builtin_amdgcn_mfma_f32_16x16x32_f16(qv_f[ks], b1, acc[1], 0, 0, 0);
            }
#pragma unroll
            for (int nt = 0; nt < 2; ++nt)
#pragma unroll
                for (int rr = 0; rr < 4; ++rr) {
                    int m = m_off + (lane >> 4) * 4 + rr;
                    int p = j0 + n_off + nt * 16 + fr;
                    int pr = p + i0 + m;
                    f16 v = (f16)acc[nt][rr];
                    if (pr >= 1023) {
                        Ssc[m * SST + (pr - 1023)] = v;
                    } else if (m > 0) {
                        Ssc[(m - 1) * SST + (pr + 1)] = v;
                    }
                }
            __syncthreads();
        }
    }

    // diagonal zeros: shifted[r][r+1] = 0
    if (tid < 32) {
        int c = i0 + tid + 1;
        if (c < 1024) Ssc[tid * SST + c] = (f16)0.f;
    }

    // ---- phase 1b: row-31 tail from raw row i0+32 (only valid dest cols) ----
    if (i0 + 32 < 1024) {
        int base = tid * 4;
        if (base + i0 + 33 <= 1023) {
#pragma unroll
            for (int pi = 0; pi < 4; ++pi) {
                int p = base + pi;
                int s = p + i0 + 33;
                if (s <= 1023) {
                    const f16* pr = Pp + (size_t)p * 64;
                    float sacc = 0.f;
#pragma unroll
                    for (int c = 0; c < 64; c += 8) {
                        f16x8 pv = *(const f16x8*)(pr + c);
                        f16x8 qv8 = *(const f16x8*)(qxrow + c);
#pragma unroll
                        for (int j = 0; j < 8; ++j) sacc += (float)pv[j] * (float)qv8[j];
                    }
                    Ssc[31 * SST + s] = (f16)sacc;
                }
            }
        }
    }

    // ---- phase 3: scores = (shiftedBD + q_u @ kh^T) * 0.125, in place ----
    {
        f16x8 pf0, pf1;
        {
            const f16* s = Kh + (size_t)srow * 64 + sc0;
            pf0 = *(const f16x8*)(s);
            pf1 = *(const f16x8*)(s + 8);
        }
        for (int j0 = 0; j0 < 1024; j0 += 64) {
            *(f16x8*)(Bt + srow * BST + sc0) = pf0;
            *(f16x8*)(Bt + srow * BST + sc0 + 8) = pf1;
            __syncthreads();
            if (j0 + 64 < 1024) {
                const f16* s = Kh + (size_t)(j0 + 64 + srow) * 64 + sc0;
                pf0 = *(const f16x8*)(s);
                pf1 = *(const f16x8*)(s + 8);
            }
            f32x4 acc[2] = {zero, zero};
#pragma unroll
            for (int ks = 0; ks < 2; ++ks) {
                f16x8 b0 = *(const f16x8*)(Bt + (n_off + fr) * BST + ks * 32 + kq);
                f16x8 b1 = *(const f16x8*)(Bt + (n_off + 16 + fr) * BST + ks * 32 + kq);
                acc[0] = __builtin_amdgcn_mfma_f32_16x16x32_f16(qu_f[ks], b0, acc[0], 0, 0, 0);
                acc[1] = __builtin_amdgcn_mfma_f32_16x16x32_f16(qu_f[ks], b1, acc[1], 0, 0, 0);
            }
#pragma unroll
            for (int nt = 0; nt < 2; ++nt)
#pragma unroll
                for (int rr = 0; rr < 4; ++rr) {
                    int m = m_off + (lane >> 4) * 4 + rr;
                    int c = j0 + n_off + nt * 16 + fr;
                    float sc = ((float)Ssc[m * SST + c] + acc[nt][rr]) * 0.125f;
                    Ssc[m * SST + c] = (f16)sc;
                }
            __syncthreads();
        }
    }

    // ---- phase 4: mask + softmax; conflict-free col mapping (lane*8, 512+lane*8) ----
    float* Ab = attn + (size_t)bh * 1048576;
    const int* MK = mask + ((size_t)b * 1024 + i0) * 1024;
    for (int rr = 0; rr < 8; ++rr) {
        int lr = w * 8 + rr;
        int c0 = lane * 8;
        int c1 = 512 + lane * 8;
        f16x8 a0 = *(const f16x8*)(Ssc + lr * SST + c0);
        f16x8 a1 = *(const f16x8*)(Ssc + lr * SST + c1);
        const int* mrow = MK + (size_t)lr * 1024;
        int4 mk0 = *(const int4*)(mrow + c0);
        int4 mk1 = *(const int4*)(mrow + c0 + 4);
        int4 mk2 = *(const int4*)(mrow + c1);
        int4 mk3 = *(const int4*)(mrow + c1 + 4);
        int mks[16] = {mk0.x, mk0.y, mk0.z, mk0.w, mk1.x, mk1.y, mk1.z, mk1.w,
                       mk2.x, mk2.y, mk2.z, mk2.w, mk3.x, mk3.y, mk3.z, mk3.w};
        float vals[16];
        float mx = -1e30f;
#pragma unroll
        for (int j = 0; j < 16; ++j) {
            float v = (j < 8) ? (float)a0[j] : (float)a1[j - 8];
            if (mks[j] == 0) v = -10000.0f;
            vals[j] = v;
            mx = fmaxf(mx, v);
        }
#pragma unroll
        for (int off = 32; off > 0; off >>= 1) mx = fmaxf(mx, __shfl_xor(mx, off));
        float sum = 0.f;
#pragma unroll
        for (int j = 0; j < 16; ++j) { vals[j] = __expf(vals[j] - mx); sum += vals[j]; }
#pragma unroll
        for (int off = 32; off > 0; off >>= 1) sum += __shfl_xor(sum, off);
        float il = 1.f / sum;
        float* arow = Ab + (size_t)(i0 + lr) * 1024;
        float4 f0 = {vals[0] * il, vals[1] * il, vals[2] * il, vals[3] * il};
        float4 f1 = {vals[4] * il, vals[5] * il, vals[6] * il, vals[7] * il};
        float4 f2 = {vals[8] * il, vals[9] * il, vals[10] * il, vals[11] * il};
        float4 f3 = {vals[12] * il, vals[13] * il, vals[14] * il, vals[15] * il};
        *(float4*)(arow + c0) = f0;
        *(float4*)(arow + c0 + 4) = f1;
        *(float4*)(arow + c1) = f2;
        *(float4*)(arow + c1 + 4) = f3;
        f16x8 p0, p1;
#pragma unroll
        for (int j = 0; j < 8; ++j) {
            p0[j] = (f16)(vals[j] * il);
            p1[j] = (f16)(vals[8 + j] * il);
        }
        *(f16x8*)(Ssc + lr * SST + c0) = p0;
        *(f16x8*)(Ssc + lr * SST + c1) = p1;
    }

    // ---- phase 5: PV = probs @ V ----
    f32x4 accp[2] = {zero, zero};
    {
        f16x8 pf0, pf1;
        {
            const f16* s = Vt + (size_t)srow * 1024 + sc0;
            pf0 = *(const f16x8*)(s);
            pf1 = *(const f16x8*)(s + 8);
        }
        for (int j0 = 0; j0 < 1024; j0 += 64) {
            *(f16x8*)(Bt + srow * BST + sc0) = pf0;
            *(f16x8*)(Bt + srow * BST + sc0 + 8) = pf1;
            __syncthreads();
            if (j0 + 64 < 1024) {
                const f16* s = Vt + (size_t)srow * 1024 + j0 + 64 + sc0;
                pf0 = *(const f16x8*)(s);
                pf1 = *(const f16x8*)(s + 8);
            }
#pragma unroll
            for (int ks = 0; ks < 2; ++ks) {
                f16x8 a0 = *(const f16x8*)(Ssc + (m_off + fr) * SST + j0 + ks * 32 + kq);
                f16x8 b0 = *(const f16x8*)(Bt + (n_off + fr) * BST + ks * 32 + kq);
                f16x8 b1 = *(const f16x8*)(Bt + (n_off + 16 + fr) * BST + ks * 32 + kq);
                accp[0] = __builtin_amdgcn_mfma_f32_16x16x32_f16(a0, b0, accp[0], 0, 0, 0);
                accp[1] = __builtin_amdgcn_mfma_f32_16x16x32_f16(a0, b1, accp[1], 0, 0, 0);
            }
            __syncthreads();
        }
    }
#pragma unroll
    for (int nt = 0; nt < 2; ++nt)
#pragma unroll
        for (int rr = 0; rr < 4; ++rr) {
            int t = i0 + m_off + (lane >> 4) * 4 + rr;
            int d = n_off + nt * 16 + fr;
            oh[((size_t)(b * 1024 + t)) * 1024 + h * 64 + d] = (f16)accp[nt][rr];
        }
}

// output = concat @ Wo^T + bo (fp32 out)
__global__ __launch_bounds__(256) void out_gemm(const f16* __restrict__ A,
                                                const f16* __restrict__ W,
                                                const float* __restrict__ bias,
                                                float* __restrict__ out) {
    GEMM_PROLOGUE();
    const int m0 = blockIdx.y * 64;
    const int n0 = blockIdx.x * 64;
    GEMM_KLOOP(A + (size_t)m0 * 1024, W + (size_t)n0 * 1024);
#pragma unroll
    for (int mt = 0; mt < 2; ++mt)
#pragma unroll
        for (int nt = 0; nt < 2; ++nt)
#pragma unroll
            for (int rr = 0; rr < 4; ++rr) {
                int m = m0 + m_off + mt * 16 + (lane >> 4) * 4 + rr;
                int n = n0 + n_off + nt * 16 + (lane & 15);
                out[(size_t)m * 1024 + n] = acc[mt][nt][rr] + bias[n];
            }
}

extern "C" void kernel_launch(void* const* d_in, const int* in_sizes, int n_in,
                              void* d_out, int out_size, void* d_ws, size_t ws_size,
                              hipStream_t stream) {
    (void)in_sizes; (void)n_in; (void)out_size; (void)ws_size;
    const float* q   = (const float*)d_in[0];
    const float* k   = (const float*)d_in[1];
    const float* v   = (const float*)d_in[2];
    const float* pe  = (const float*)d_in[3];
    const int*   msk = (const int*)d_in[4];
    const float* Wq  = (const float*)d_in[5];
    const float* bq  = (const float*)d_in[6];
    const float* Wk  = (const float*)d_in[7];
    const float* bk  = (const float*)d_in[8];
    const float* Wv  = (const float*)d_in[9];
    const float* bv  = (const float*)d_in[10];
    const float* Wp  = (const float*)d_in[11];
    const float* pbu = (const float*)d_in[12];
    const float* pbv = (const float*)d_in[13];
    const float* Wo  = (const float*)d_in[14];
    const float* bo  = (const float*)d_in[15];

    char* ws = (char*)d_ws;
    f16* cvt = (f16*)(ws + 0);  // 36 MB: q,k,v,pe,Wq,Wk,Wv,Wp,Wo in f16
    f16* qf  = cvt;
    f16* kf  = cvt + 4194304;
    f16* vf  = cvt + 8388608;
    f16* pef = cvt + 12582912;
    f16* Wqf = cvt + 13631488;
    f16* Wkf = cvt + 14680064;
    f16* Wvf = cvt + 15728640;
    f16* Wpf = cvt + 16777216;
    f16* Wof = cvt + 17825792;

    f16* q_u = (f16*)(ws + 37748736);   //  8 MB  [b][h][t][64]
    f16* q_v = (f16*)(ws + 46137344);   //  8 MB
    f16* kh  = (f16*)(ws + 54525952);   //  8 MB
    f16* vh  = (f16*)(ws + 62914560);   //  8 MB
    f16* pp  = (f16*)(ws + 71303168);   //  2 MB  [h][pos][64]
    f16* oh  = (f16*)(ws + 73400320);   //  8 MB  [b][t][h*64+d]
    f16* vT  = (f16*)(ws + 81788928);   //  8 MB  [b][h][d][s]

    float* out  = (float*)d_out;
    float* attn = out + 4194304;

    dim3 blk(256);
    cvt_all<<<dim3(1024, 9), blk, 0, stream>>>(q, k, v, pe, Wq, Wk, Wv, Wp, Wo, cvt);
    proj_qkv<<<dim3(16, 64, 3), blk, 0, stream>>>(qf, kf, vf, Wqf, Wkf, Wvf, bq, bk, bv,
                                                  pbu, pbv, q_u, q_v, kh, vh);
    proj_p<<<dim3(16, 16), blk, 0, stream>>>(pef, Wpf, pp);
    transpose_v<<<dim3(16, 64), blk, 0, stream>>>(vh, vT);
    fused_attn<<<dim3(32, 64), blk, 0, stream>>>(q_u, q_v, kh, pp, vT, msk, attn, oh);
    out_gemm<<<dim3(16, 64), blk, 0, stream>>>(oh, Wof, bo, out);
}